// Round 1
// baseline (998.086 us; speedup 1.0000x reference)
//
#include <hip/hip_runtime.h>
#include <hip/hip_bf16.h>
#include <math.h>

#define Bn 16
#define Pn 500
#define Nn 501
#define En 128
#define Hn 8
#define HDn 16
#define Ln 3
#define ROWS (Bn*Nn)   // 8016
#define LEAKY 0.2f
#define LN_EPS 1e-5f

// ---------------- K0: embedding ----------------
__global__ __launch_bounds__(256) void embed_kernel(
    const float* __restrict__ depot, const float* __restrict__ node,
    const float* __restrict__ depW, const float* __restrict__ depB,
    const float* __restrict__ nodeW, const float* __restrict__ nodeB,
    float* __restrict__ x) {
  int idx = blockIdx.x * 256 + threadIdx.x;
  if (idx >= ROWS * En) return;
  int row = idx / En, e = idx % En;
  int b = row / Nn, n = row % Nn;
  float v;
  if (n == 0) {
    v = depB[e] + depot[b * 2 + 0] * depW[0 * En + e]
                + depot[b * 2 + 1] * depW[1 * En + e];
  } else {
    const float* np_ = node + (b * Pn + (n - 1)) * 5;
    v = nodeB[e];
#pragma unroll
    for (int k = 0; k < 5; k++) v += np_[k] * nodeW[k * En + e];
  }
  x[idx] = v;
}

// ---------------- K1: xW = x @ W[l]  (8016x128 @ 128x128, f32) ----------------
__global__ __launch_bounds__(256) void gemm_xw(
    const float* __restrict__ x, const float* __restrict__ Wl,
    float* __restrict__ xw) {
  __shared__ float As[64][33];
  __shared__ float Bs[32][128];
  int tid = threadIdx.x;
  int row0 = blockIdx.x * 64;
  int tc = tid % 32;   // col group (4 cols each)
  int trg = tid / 32;  // row group (8 rows each)
  float acc[8][4];
#pragma unroll
  for (int m = 0; m < 8; m++)
#pragma unroll
    for (int n = 0; n < 4; n++) acc[m][n] = 0.f;

  for (int k0 = 0; k0 < 128; k0 += 32) {
#pragma unroll
    for (int s = 0; s < 8; s++) {   // A tile 64x32
      int a = tid + s * 256;
      int r = a >> 5, c = a & 31;
      int gr = row0 + r;
      As[r][c] = (gr < ROWS) ? x[gr * 128 + k0 + c] : 0.f;
    }
#pragma unroll
    for (int s = 0; s < 16; s++) {  // B tile 32x128
      int a2 = tid + s * 256;
      int r = a2 >> 7, c = a2 & 127;
      Bs[r][c] = Wl[(k0 + r) * 128 + c];
    }
    __syncthreads();
#pragma unroll
    for (int kk = 0; kk < 32; kk++) {
      float bv[4];
#pragma unroll
      for (int n = 0; n < 4; n++) bv[n] = Bs[kk][tc * 4 + n];
#pragma unroll
      for (int m = 0; m < 8; m++) {
        float av = As[trg * 8 + m][kk];
#pragma unroll
        for (int n = 0; n < 4; n++) acc[m][n] += av * bv[n];
      }
    }
    __syncthreads();
  }
#pragma unroll
  for (int m = 0; m < 8; m++) {
    int gr = row0 + trg * 8 + m;
    if (gr < ROWS) {
#pragma unroll
      for (int n = 0; n < 4; n++) xw[gr * 128 + tc * 4 + n] = acc[m][n];
    }
  }
}

// ---------------- K1b: ei/ej per (row, head) ----------------
__global__ __launch_bounds__(256) void eij_kernel(
    const float* __restrict__ xw, const float* __restrict__ attn_l,
    float* __restrict__ ei, float* __restrict__ ej) {
  int idx = blockIdx.x * 256 + threadIdx.x;
  if (idx >= ROWS * Hn) return;
  int row = idx >> 3, h = idx & 7;
  const float* xr = xw + row * 128 + h * 16;
  const float* a1 = attn_l + h * 32;
  const float* a2 = a1 + 16;
  float s1 = 0.f, s2 = 0.f;
#pragma unroll
  for (int d = 0; d < 16; d++) {
    float v = xr[d];
    s1 += v * a1[d];
    s2 += v * a2[d];
  }
  ei[idx] = s1;
  ej[idx] = s2;
}

// ---------------- K2: attention + residual + LN + ELU, block per (b,i) ----------------
__global__ __launch_bounds__(256) void attn_ln_kernel(
    const float* __restrict__ xw, const float* __restrict__ ei,
    const float* __restrict__ ej, const int* __restrict__ adj,
    const float* __restrict__ g, const float* __restrict__ bb,
    float* __restrict__ out) {
  __shared__ float sp[Nn * Hn];  // 4008 floats = 16 KB
  __shared__ float sred[256];
  __shared__ float smax[Hn], ssum[Hn];
  int blk = blockIdx.x;
  int b = blk / Nn, i = blk % Nn;
  int t = threadIdx.x;
  const float* eib = ei + (b * Nn + i) * Hn;
  const float* ejb = ej + b * Nn * Hn;
  const int* adjr = adj + (b * Nn + i) * Nn;

  // pass 1: masked leaky-relu scores
  for (int idx = t; idx < Nn * Hn; idx += 256) {
    int j = idx >> 3, h = idx & 7;
    float e = eib[h] + ejb[idx];
    e = (e >= 0.f) ? e : LEAKY * e;
    if (adjr[j] == 0) e = -INFINITY;
    sp[idx] = e;
  }
  __syncthreads();

  // per-head max (threads: h = t&7, k = t>>3 in [0,32))
  {
    int h = t & 7, k = t >> 3;
    float m = -INFINITY;
    for (int j = k; j < Nn; j += 32) m = fmaxf(m, sp[j * Hn + h]);
    sred[t] = m;
    __syncthreads();
    for (int off = 16; off >= 1; off >>= 1) {
      if (k < off) sred[t] = fmaxf(sred[t], sred[t + off * 8]);
      __syncthreads();
    }
    if (t < Hn) smax[t] = sred[t];
    __syncthreads();
  }
  // exp in place + per-head sum
  {
    int h = t & 7, k = t >> 3;
    float m = smax[h];
    float s = 0.f;
    for (int j = k; j < Nn; j += 32) {
      float p = __expf(sp[j * Hn + h] - m);
      sp[j * Hn + h] = p;
      s += p;
    }
    sred[t] = s;
    __syncthreads();
    for (int off = 16; off >= 1; off >>= 1) {
      if (k < off) sred[t] += sred[t + off * 8];
      __syncthreads();
    }
    if (t < Hn) ssum[t] = sred[t];
    __syncthreads();
  }

  // pass 3: out[h,d] = sum_j p[j,h]*xW[b,j,h*16+d]; j split across 2 halves
  int pr = t & 127;  // = h*16+d
  int h3 = pr >> 4;
  int half = t >> 7;
  float acc = 0.f;
  for (int j = half; j < Nn; j += 2) {
    float w = sp[j * Hn + h3];
    acc += w * xw[(b * Nn + j) * 128 + pr];
  }
  sred[t] = acc;
  __syncthreads();

  float y = 0.f;
  if (t < 128) {
    float o = (sred[t] + sred[t + 128]) / ssum[h3];
    y = o + xw[(b * Nn + i) * 128 + t];  // residual with xW
  }
  __syncthreads();
  sred[t] = (t < 128) ? y : 0.f;
  __syncthreads();
  for (int off = 64; off >= 1; off >>= 1) {
    if (t < off) sred[t] += sred[t + off];
    __syncthreads();
  }
  float mu = sred[0] / 128.f;
  __syncthreads();
  sred[t] = (t < 128) ? (y - mu) * (y - mu) : 0.f;
  __syncthreads();
  for (int off = 64; off >= 1; off >>= 1) {
    if (t < off) sred[t] += sred[t + off];
    __syncthreads();
  }
  float var = sred[0] / 128.f;
  if (t < 128) {
    float z = (y - mu) * rsqrtf(var + LN_EPS) * g[t] + bb[t];
    out[(b * Nn + i) * 128 + t] = (z > 0.f) ? z : expm1f(z);
  }
}

extern "C" void kernel_launch(void* const* d_in, const int* in_sizes, int n_in,
                              void* d_out, int out_size, void* d_ws, size_t ws_size,
                              hipStream_t stream) {
  const float* depot = (const float*)d_in[0];
  const float* node  = (const float*)d_in[1];
  const int*   adj   = (const int*)d_in[2];
  const float* depW  = (const float*)d_in[3];
  const float* depB  = (const float*)d_in[4];
  const float* nodeW = (const float*)d_in[5];
  const float* nodeB = (const float*)d_in[6];
  const float* W     = (const float*)d_in[7];
  const float* attn  = (const float*)d_in[8];
  const float* lng   = (const float*)d_in[9];
  const float* lnb   = (const float*)d_in[10];
  float* out = (float*)d_out;

  float* xa = (float*)d_ws;
  float* xw = xa + (size_t)ROWS * En;
  float* ei = xw + (size_t)ROWS * En;
  float* ej = ei + (size_t)ROWS * Hn;

  embed_kernel<<<(ROWS * En + 255) / 256, 256, 0, stream>>>(
      depot, node, depW, depB, nodeW, nodeB, xa);

  for (int l = 0; l < Ln; l++) {
    gemm_xw<<<(ROWS + 63) / 64, 256, 0, stream>>>(xa, W + (size_t)l * En * En, xw);
    eij_kernel<<<(ROWS * Hn + 255) / 256, 256, 0, stream>>>(
        xw, attn + (size_t)l * Hn * 2 * HDn, ei, ej);
    float* dst = (l == Ln - 1) ? out : xa;
    attn_ln_kernel<<<Bn * Nn, 256, 0, stream>>>(
        xw, ei, ej, adj, lng + (size_t)l * En, lnb + (size_t)l * En, dst);
  }
}

// Round 2
// 259.174 us; speedup vs baseline: 3.8510x; 3.8510x over previous
//
#include <hip/hip_runtime.h>
#include <hip/hip_bf16.h>
#include <math.h>

#define Bn 16
#define Pn 500
#define Nn 501
#define En 128
#define Hn 8
#define HDn 16
#define Ln 3
#define ROWS (Bn*Nn)   // 8016
#define LN_EPS 1e-5f

typedef __attribute__((ext_vector_type(8))) short bf16x8;
typedef __attribute__((ext_vector_type(4))) float f32x4;

__device__ inline short f2bf(float x) {
  __hip_bfloat16 h = __float2bfloat16(x);
  return *reinterpret_cast<short*>(&h);
}
__device__ inline float bf2f(short s) {
  __hip_bfloat16 h = *reinterpret_cast<__hip_bfloat16*>(&s);
  return __bfloat162float(h);
}

// ---------------- K0: embedding ----------------
__global__ __launch_bounds__(256) void embed_kernel(
    const float* __restrict__ depot, const float* __restrict__ node,
    const float* __restrict__ depW, const float* __restrict__ depB,
    const float* __restrict__ nodeW, const float* __restrict__ nodeB,
    float* __restrict__ x) {
  int idx = blockIdx.x * 256 + threadIdx.x;
  if (idx >= ROWS * En) return;
  int row = idx / En, e = idx % En;
  int b = row / Nn, n = row % Nn;
  float v;
  if (n == 0) {
    v = depB[e] + depot[b * 2 + 0] * depW[0 * En + e]
                + depot[b * 2 + 1] * depW[1 * En + e];
  } else {
    const float* np_ = node + (b * Pn + (n - 1)) * 5;
    v = nodeB[e];
#pragma unroll
    for (int k = 0; k < 5; k++) v += np_[k] * nodeW[k * En + e];
  }
  x[idx] = v;
}

// ---------------- adjacency bit-pack: block per (b, i), 512 threads ----------------
__global__ __launch_bounds__(512) void adjpack_kernel(
    const int* __restrict__ adj, unsigned* __restrict__ bits) {
  int blk = blockIdx.x;
  int b = blk >> 9, i = blk & 511;
  int gi = (i < Nn) ? i : (Nn - 1);
  int t = threadIdx.x;
  int v = (t < Nn) ? adj[((size_t)b * Nn + gi) * Nn + t] : 0;
  unsigned long long mask = __ballot(v != 0);
  int wave = t >> 6;
  if ((t & 63) == 0) {
    unsigned* wp = bits + ((size_t)b * 512 + i) * 16 + wave * 2;
    wp[0] = (unsigned)(mask & 0xffffffffull);
    wp[1] = (unsigned)(mask >> 32);
  }
}

// ---------------- K1: xW = x @ W[l]  (8016x128 @ 128x128, f32) ----------------
__global__ __launch_bounds__(256) void gemm_xw(
    const float* __restrict__ x, const float* __restrict__ Wl,
    float* __restrict__ xw) {
  __shared__ float As[64][33];
  __shared__ float Bs[32][128];
  int tid = threadIdx.x;
  int row0 = blockIdx.x * 64;
  int tc = tid % 32;
  int trg = tid / 32;
  float acc[8][4];
#pragma unroll
  for (int m = 0; m < 8; m++)
#pragma unroll
    for (int n = 0; n < 4; n++) acc[m][n] = 0.f;

  for (int k0 = 0; k0 < 128; k0 += 32) {
#pragma unroll
    for (int s = 0; s < 8; s++) {
      int a = tid + s * 256;
      int r = a >> 5, c = a & 31;
      int gr = row0 + r;
      As[r][c] = (gr < ROWS) ? x[gr * 128 + k0 + c] : 0.f;
    }
#pragma unroll
    for (int s = 0; s < 16; s++) {
      int a2 = tid + s * 256;
      int r = a2 >> 7, c = a2 & 127;
      Bs[r][c] = Wl[(k0 + r) * 128 + c];
    }
    __syncthreads();
#pragma unroll
    for (int kk = 0; kk < 32; kk++) {
      float bv[4];
#pragma unroll
      for (int n = 0; n < 4; n++) bv[n] = Bs[kk][tc * 4 + n];
#pragma unroll
      for (int m = 0; m < 8; m++) {
        float av = As[trg * 8 + m][kk];
#pragma unroll
        for (int n = 0; n < 4; n++) acc[m][n] += av * bv[n];
      }
    }
    __syncthreads();
  }
#pragma unroll
  for (int m = 0; m < 8; m++) {
    int gr = row0 + trg * 8 + m;
    if (gr < ROWS) {
#pragma unroll
      for (int n = 0; n < 4; n++) xw[gr * 128 + tc * 4 + n] = acc[m][n];
    }
  }
}

// ---------------- K1b: ei/ej per (row, head) ----------------
__global__ __launch_bounds__(256) void eij_kernel(
    const float* __restrict__ xw, const float* __restrict__ attn_l,
    float* __restrict__ ei, float* __restrict__ ej) {
  int idx = blockIdx.x * 256 + threadIdx.x;
  if (idx >= ROWS * Hn) return;
  int row = idx >> 3, h = idx & 7;
  const float* xr = xw + row * 128 + h * 16;
  const float* a1 = attn_l + h * 32;
  const float* a2 = a1 + 16;
  float s1 = 0.f, s2 = 0.f;
#pragma unroll
  for (int d = 0; d < 16; d++) {
    float v = xr[d];
    s1 += v * a1[d];
    s2 += v * a2[d];
  }
  ei[idx] = s1;
  ej[idx] = s2;
}

// ---------------- K2: flash-style MFMA attention + residual + LN + ELU ----------------
// block = (b, i-tile of 32); 512 threads = 8 waves = 8 heads; 256 blocks total.
__global__ __launch_bounds__(512) void attn_fused(
    const float* __restrict__ xw, const float* __restrict__ ei,
    const float* __restrict__ ej, const unsigned* __restrict__ adjbits,
    const float* __restrict__ g, const float* __restrict__ bb,
    float* __restrict__ dst) {
  __shared__ float ejl[Hn][516];       // [h][j] padded -> conflict-free frag reads
  __shared__ float Vt[64][132];        // j-tile of xw (f32)
  __shared__ unsigned adjw[32][17];    // bitmask words for our 32 rows
  __shared__ float oout[32][132];      // attention output for LN phase

  int blk = blockIdx.x;
  int b = blk >> 4;
  int i0 = (blk & 15) << 5;
  int t = threadIdx.x;
  int h = t >> 6;          // wave == head
  int lane = t & 63;
  int li = lane & 15;      // A/C row-in-frag ; B/C col
  int lg = lane >> 4;      // k-group

  // stage ej transposed [h][j]
  for (int s = t; s < 512 * Hn; s += 512) {
    int j = s >> 3, hh = s & 7;
    ejl[hh][j] = (j < Nn) ? ej[((size_t)b * Nn + j) * Hn + hh] : 0.f;
  }
  // stage adjacency words
  for (int s = t; s < 32 * 16; s += 512) {
    int r = s >> 4, w = s & 15;
    int gi = i0 + r; if (gi >= Nn) gi = Nn - 1;
    adjw[r][w] = adjbits[((size_t)b * 512 + gi) * 16 + w];
  }

  int gi0 = i0 + li;      if (gi0 >= Nn) gi0 = Nn - 1;
  int gi1 = i0 + 16 + li; if (gi1 >= Nn) gi1 = Nn - 1;
  float eiv0 = ei[((size_t)b * Nn + gi0) * Hn + h];
  float eiv1 = ei[((size_t)b * Nn + gi1) * Hn + h];

  f32x4 acc0 = {0.f, 0.f, 0.f, 0.f};
  f32x4 acc1 = {0.f, 0.f, 0.f, 0.f};
  float m0 = -1e30f, m1 = -1e30f, l0 = 0.f, l1 = 0.f;

  for (int jt = 0; jt < 8; ++jt) {
    int j0 = jt << 6;
    __syncthreads();   // previous V tile fully consumed
    // stage V tile: xw[b, j0..j0+63, 0..127]
    for (int s = t; s < 64 * 32; s += 512) {
      int jj = s >> 5, c4 = (s & 31) << 2;
      int gj = j0 + jj;
      float4 v;
      if (gj < Nn) v = *(const float4*)&xw[((size_t)b * Nn + gj) * En + c4];
      else         v = make_float4(0.f, 0.f, 0.f, 0.f);
      *(float4*)&Vt[jj][c4] = v;
    }
    __syncthreads();

    // ---- scores in A-frag layout: j = j0 + kw*32 + lg*8 + e ----
    float sc0[2][8], sc1[2][8];
#pragma unroll
    for (int kw = 0; kw < 2; ++kw) {
      const float* pj = &ejl[h][j0 + (kw << 5) + (lg << 3)];
      unsigned mb0 = (adjw[li][(j0 >> 5) + kw] >> (lg << 3)) & 0xffu;
      unsigned mb1 = (adjw[16 + li][(j0 >> 5) + kw] >> (lg << 3)) & 0xffu;
#pragma unroll
      for (int e = 0; e < 8; ++e) {
        float ejv = pj[e];
        float s0 = eiv0 + ejv; s0 = fmaxf(s0, 0.2f * s0);
        float s1 = eiv1 + ejv; s1 = fmaxf(s1, 0.2f * s1);
        sc0[kw][e] = ((mb0 >> e) & 1u) ? s0 : -INFINITY;
        sc1[kw][e] = ((mb1 >> e) & 1u) ? s1 : -INFINITY;
      }
    }
    // ---- row max (rows are lane-local at l&15; reduce across k-groups) ----
    float tm0 = -INFINITY, tm1 = -INFINITY;
#pragma unroll
    for (int kw = 0; kw < 2; ++kw)
#pragma unroll
      for (int e = 0; e < 8; ++e) {
        tm0 = fmaxf(tm0, sc0[kw][e]);
        tm1 = fmaxf(tm1, sc1[kw][e]);
      }
    tm0 = fmaxf(tm0, __shfl_xor(tm0, 16)); tm0 = fmaxf(tm0, __shfl_xor(tm0, 32));
    tm1 = fmaxf(tm1, __shfl_xor(tm1, 16)); tm1 = fmaxf(tm1, __shfl_xor(tm1, 32));
    float mn0 = fmaxf(m0, tm0), mn1 = fmaxf(m1, tm1);
    float fr0 = __expf(m0 - mn0), fr1 = __expf(m1 - mn1);
    m0 = mn0; m1 = mn1;

    // ---- p = exp(s - m), bf16 hi/lo split, tile sums ----
    float ts0 = 0.f, ts1 = 0.f;
    short ph0[2][8], pl0[2][8], ph1[2][8], pl1[2][8];
#pragma unroll
    for (int kw = 0; kw < 2; ++kw)
#pragma unroll
      for (int e = 0; e < 8; ++e) {
        float p0 = __expf(sc0[kw][e] - mn0);
        float p1 = __expf(sc1[kw][e] - mn1);
        ts0 += p0; ts1 += p1;
        short h0 = f2bf(p0); ph0[kw][e] = h0; pl0[kw][e] = f2bf(p0 - bf2f(h0));
        short h1 = f2bf(p1); ph1[kw][e] = h1; pl1[kw][e] = f2bf(p1 - bf2f(h1));
      }
    ts0 += __shfl_xor(ts0, 16); ts0 += __shfl_xor(ts0, 32);
    ts1 += __shfl_xor(ts1, 16); ts1 += __shfl_xor(ts1, 32);
    l0 = l0 * fr0 + ts0;
    l1 = l1 * fr1 + ts1;

    // ---- rescale accumulators (C rows = lg*4 + r) ----
    int base = lg << 2;
#pragma unroll
    for (int r = 0; r < 4; ++r) {
      acc0[r] *= __shfl(fr0, base + r);
      acc1[r] *= __shfl(fr1, base + r);
    }

    // ---- V frags + MFMA (hi*hi + hi*lo + lo*hi) ----
#pragma unroll
    for (int kw = 0; kw < 2; ++kw) {
      short vh[8], vl[8];
#pragma unroll
      for (int e = 0; e < 8; ++e) {
        float v = Vt[(kw << 5) + (lg << 3) + e][h * 16 + li];
        short hv = f2bf(v); vh[e] = hv; vl[e] = f2bf(v - bf2f(hv));
      }
      bf16x8 vbh = {vh[0], vh[1], vh[2], vh[3], vh[4], vh[5], vh[6], vh[7]};
      bf16x8 vbl = {vl[0], vl[1], vl[2], vl[3], vl[4], vl[5], vl[6], vl[7]};
      bf16x8 pah0 = {ph0[kw][0], ph0[kw][1], ph0[kw][2], ph0[kw][3],
                     ph0[kw][4], ph0[kw][5], ph0[kw][6], ph0[kw][7]};
      bf16x8 pal0 = {pl0[kw][0], pl0[kw][1], pl0[kw][2], pl0[kw][3],
                     pl0[kw][4], pl0[kw][5], pl0[kw][6], pl0[kw][7]};
      bf16x8 pah1 = {ph1[kw][0], ph1[kw][1], ph1[kw][2], ph1[kw][3],
                     ph1[kw][4], ph1[kw][5], ph1[kw][6], ph1[kw][7]};
      bf16x8 pal1 = {pl1[kw][0], pl1[kw][1], pl1[kw][2], pl1[kw][3],
                     pl1[kw][4], pl1[kw][5], pl1[kw][6], pl1[kw][7]};
      acc0 = __builtin_amdgcn_mfma_f32_16x16x32_bf16(pah0, vbh, acc0, 0, 0, 0);
      acc0 = __builtin_amdgcn_mfma_f32_16x16x32_bf16(pah0, vbl, acc0, 0, 0, 0);
      acc0 = __builtin_amdgcn_mfma_f32_16x16x32_bf16(pal0, vbh, acc0, 0, 0, 0);
      acc1 = __builtin_amdgcn_mfma_f32_16x16x32_bf16(pah1, vbh, acc1, 0, 0, 0);
      acc1 = __builtin_amdgcn_mfma_f32_16x16x32_bf16(pah1, vbl, acc1, 0, 0, 0);
      acc1 = __builtin_amdgcn_mfma_f32_16x16x32_bf16(pal1, vbh, acc1, 0, 0, 0);
    }
  }

  // ---- normalize, write to LDS for LN phase ----
  {
    int base = lg << 2;
#pragma unroll
    for (int r = 0; r < 4; ++r) {
      float d0 = __shfl(l0, base + r);
      float d1 = __shfl(l1, base + r);
      oout[base + r][h * 16 + li] = acc0[r] / d0;
      oout[16 + base + r][h * 16 + li] = acc1[r] / d1;
    }
  }
  __syncthreads();

  // ---- residual + LayerNorm + ELU: 16 threads per row, 8 cols each ----
  {
    int row = t >> 4;
    int c0 = (t & 15) << 3;
    int gi = i0 + row;
    bool valid = gi < Nn;
    int gic = valid ? gi : Nn - 1;
    const float* xr = &xw[((size_t)b * Nn + gic) * En + c0];
    float4 o1 = *(float4*)&oout[row][c0];
    float4 o2 = *(float4*)&oout[row][c0 + 4];
    float4 x1 = *(const float4*)xr;
    float4 x2 = *(const float4*)(xr + 4);
    float y[8];
    y[0] = o1.x + x1.x; y[1] = o1.y + x1.y; y[2] = o1.z + x1.z; y[3] = o1.w + x1.w;
    y[4] = o2.x + x2.x; y[5] = o2.y + x2.y; y[6] = o2.z + x2.z; y[7] = o2.w + x2.w;
    float sum = 0.f, sq = 0.f;
#pragma unroll
    for (int u = 0; u < 8; ++u) { sum += y[u]; sq += y[u] * y[u]; }
#pragma unroll
    for (int mk = 1; mk <= 8; mk <<= 1) {
      sum += __shfl_xor(sum, mk);
      sq  += __shfl_xor(sq, mk);
    }
    float mu = sum * (1.f / 128.f);
    float var = sq * (1.f / 128.f) - mu * mu;
    float rs = rsqrtf(var + LN_EPS);
    if (valid) {
      const float4 g1 = *(const float4*)&g[c0];
      const float4 g2 = *(const float4*)&g[c0 + 4];
      const float4 b1 = *(const float4*)&bb[c0];
      const float4 b2 = *(const float4*)&bb[c0 + 4];
      float gv[8] = {g1.x, g1.y, g1.z, g1.w, g2.x, g2.y, g2.z, g2.w};
      float bv[8] = {b1.x, b1.y, b1.z, b1.w, b2.x, b2.y, b2.z, b2.w};
      float* op = &dst[((size_t)b * Nn + gi) * En + c0];
      float zo[8];
#pragma unroll
      for (int u = 0; u < 8; ++u) {
        float z = (y[u] - mu) * rs * gv[u] + bv[u];
        zo[u] = (z > 0.f) ? z : expm1f(z);
      }
      *(float4*)op = make_float4(zo[0], zo[1], zo[2], zo[3]);
      *(float4*)(op + 4) = make_float4(zo[4], zo[5], zo[6], zo[7]);
    }
  }
}

extern "C" void kernel_launch(void* const* d_in, const int* in_sizes, int n_in,
                              void* d_out, int out_size, void* d_ws, size_t ws_size,
                              hipStream_t stream) {
  const float* depot = (const float*)d_in[0];
  const float* node  = (const float*)d_in[1];
  const int*   adj   = (const int*)d_in[2];
  const float* depW  = (const float*)d_in[3];
  const float* depB  = (const float*)d_in[4];
  const float* nodeW = (const float*)d_in[5];
  const float* nodeB = (const float*)d_in[6];
  const float* W     = (const float*)d_in[7];
  const float* attn  = (const float*)d_in[8];
  const float* lng   = (const float*)d_in[9];
  const float* lnb   = (const float*)d_in[10];
  float* out = (float*)d_out;

  float* xa = (float*)d_ws;
  float* xw = xa + (size_t)ROWS * En;
  float* ei = xw + (size_t)ROWS * En;
  float* ej = ei + (size_t)ROWS * Hn;
  unsigned* adjbits = (unsigned*)(ej + (size_t)ROWS * Hn);

  adjpack_kernel<<<Bn * 512, 512, 0, stream>>>(adj, adjbits);
  embed_kernel<<<(ROWS * En + 255) / 256, 256, 0, stream>>>(
      depot, node, depW, depB, nodeW, nodeB, xa);

  for (int l = 0; l < Ln; l++) {
    gemm_xw<<<(ROWS + 63) / 64, 256, 0, stream>>>(xa, W + (size_t)l * En * En, xw);
    eij_kernel<<<(ROWS * Hn + 255) / 256, 256, 0, stream>>>(
        xw, attn + (size_t)l * Hn * 2 * HDn, ei, ej);
    float* dst = (l == Ln - 1) ? out : xa;
    attn_fused<<<Bn * 16, 512, 0, stream>>>(
        xw, ei, ej, adjbits, lng + (size_t)l * En, lnb + (size_t)l * En, dst);
  }
}